// Round 5
// baseline (529.747 us; speedup 1.0000x reference)
//
#include <hip/hip_runtime.h>
#include <hip/hip_bf16.h>

#define S_TOT 5440
#define C_DIM 256
#define F_DIM 1024
#define N_LAYERS 6

__device__ __constant__ int c_HW[4]    = {64, 32, 16, 8};
__device__ __constant__ int c_logW[4]  = {6, 5, 4, 3};
__device__ __constant__ int c_start[4] = {0, 4096, 5120, 5376};

typedef __attribute__((ext_vector_type(8))) short bf16x8;
typedef __attribute__((ext_vector_type(4))) float f32x4;

__device__ __forceinline__ short f2bf(float f) {
    __hip_bfloat16 h = __float2bfloat16(f);
    return *reinterpret_cast<short*>(&h);
}
__device__ __forceinline__ float bf2f(unsigned short u) {
    union { unsigned int i; float f; } c; c.i = ((unsigned int)u) << 16; return c.f;
}

// ---------------- weight prep: fp32 [K][N] -> bf16 [N][K], all 36 matrices ----------------
__global__ __launch_bounds__(256) void prep_weights(
    const float* __restrict__ Wv, const float* __restrict__ Woff,
    const float* __restrict__ Wattn, const float* __restrict__ Wout,
    const float* __restrict__ W1, const float* __restrict__ W2,
    unsigned short* __restrict__ WT)
{
    __shared__ short T[64][72];
    const int bid = blockIdx.x;
    const int layer = bid / 184;
    const int r = bid % 184;
    const float* src; unsigned short* dst; int K, N, kb, nb;
    if (r < 16)       { src = Wv    + (long)layer*65536;  dst = WT + 0       + (long)layer*65536;  K=256;  N=256;  kb=r&3;        nb=r>>2; }
    else if (r < 32)  { src = Woff  + (long)layer*65536;  dst = WT + 393216  + (long)layer*65536;  K=256;  N=256;  kb=(r-16)&3;   nb=(r-16)>>2; }
    else if (r < 40)  { src = Wattn + (long)layer*32768;  dst = WT + 786432  + (long)layer*32768;  K=256;  N=128;  kb=(r-32)&3;   nb=(r-32)>>2; }
    else if (r < 56)  { src = Wout  + (long)layer*65536;  dst = WT + 983040  + (long)layer*65536;  K=256;  N=256;  kb=(r-40)&3;   nb=(r-40)>>2; }
    else if (r < 120) { src = W1    + (long)layer*262144; dst = WT + 1376256 + (long)layer*262144; K=256;  N=1024; kb=(r-56)&3;   nb=(r-56)>>2; }
    else              { src = W2    + (long)layer*262144; dst = WT + 2949120 + (long)layer*262144; K=1024; N=256;  kb=(r-120)&15; nb=(r-120)>>4; }
    const int k0 = kb * 64, n0 = nb * 64;
    const int t = threadIdx.x;
    {
        const int row = t >> 2, cg = (t & 3) * 16;
        const float* sp = src + (long)(k0 + row) * N + n0 + cg;
        float4 v0 = *(const float4*)sp;
        float4 v1 = *(const float4*)(sp + 4);
        float4 v2 = *(const float4*)(sp + 8);
        float4 v3 = *(const float4*)(sp + 12);
        short tmp[16];
        tmp[0]=f2bf(v0.x); tmp[1]=f2bf(v0.y); tmp[2]=f2bf(v0.z); tmp[3]=f2bf(v0.w);
        tmp[4]=f2bf(v1.x); tmp[5]=f2bf(v1.y); tmp[6]=f2bf(v1.z); tmp[7]=f2bf(v1.w);
        tmp[8]=f2bf(v2.x); tmp[9]=f2bf(v2.y); tmp[10]=f2bf(v2.z); tmp[11]=f2bf(v2.w);
        tmp[12]=f2bf(v3.x); tmp[13]=f2bf(v3.y); tmp[14]=f2bf(v3.z); tmp[15]=f2bf(v3.w);
        *(bf16x8*)&T[row][cg]     = *(bf16x8*)&tmp[0];
        *(bf16x8*)&T[row][cg + 8] = *(bf16x8*)&tmp[8];
    }
    __syncthreads();
    {
        const int n = t >> 2, kg = (t & 3) * 16;
        short o[16];
        #pragma unroll
        for (int j = 0; j < 16; ++j) o[j] = T[kg + j][n];
        unsigned short* dp = dst + (long)(n0 + n) * K + k0 + kg;
        *(bf16x8*)dp       = *(bf16x8*)&o[0];
        *(bf16x8*)(dp + 8) = *(bf16x8*)&o[8];
    }
}

// ---------------- layer-0 activation prep ----------------
__global__ __launch_bounds__(256) void prep_x0(
    const float* __restrict__ src, const float* __restrict__ pos,
    unsigned short* __restrict__ x_bf, unsigned short* __restrict__ xp_bf)
{
    const long i = ((long)blockIdx.x * 256 + threadIdx.x) * 4;
    float4 s = *(const float4*)(src + i);
    float4 p = *(const float4*)(pos + i);
    ushort4 a, b;
    a.x = f2bf(s.x); a.y = f2bf(s.y); a.z = f2bf(s.z); a.w = f2bf(s.w);
    b.x = f2bf(s.x + p.x); b.y = f2bf(s.y + p.y); b.z = f2bf(s.z + p.z); b.w = f2bf(s.w + p.w);
    *(ushort4*)(x_bf + i) = a;
    *(ushort4*)(xp_bf + i) = b;
}

// ============ bf16 GEMM core: 64 x (NF*32) tile, BK=64, 4 waves (2x2) ============
// Wave tile: 32 x (NF*16). NF=4 -> 64x128, NF=8 -> 64x256.
template<int NF>
__device__ __forceinline__ void gemm_core(
    const unsigned short* __restrict__ A, const unsigned short* __restrict__ Bt,
    int K, int mBase, int nBase, short (*As)[72], short (*Bs)[72],
    f32x4 (&acc)[2][NF])
{
    const int t = threadIdx.x;
    const int lane = t & 63;
    const int wave = t >> 6;
    const int wr = wave >> 1, wc = wave & 1;
    const int lr = lane & 15;

    #pragma unroll
    for (int i = 0; i < 2; ++i)
        #pragma unroll
        for (int j = 0; j < NF; ++j)
            acc[i][j] = (f32x4){0.f, 0.f, 0.f, 0.f};

    for (int k0 = 0; k0 < K; k0 += 64) {
        bf16x8 ra[2], rb[NF];
        #pragma unroll
        for (int q = 0; q < 2; ++q) {
            int flat = q * 256 + t, row = flat >> 3, cg = (flat & 7) * 8;
            ra[q] = *(const bf16x8*)(A + (long)(mBase + row) * K + k0 + cg);
        }
        #pragma unroll
        for (int q = 0; q < NF; ++q) {
            int flat = q * 256 + t, row = flat >> 3, cg = (flat & 7) * 8;
            rb[q] = *(const bf16x8*)(Bt + (long)(nBase + row) * K + k0 + cg);
        }
        __syncthreads();
        #pragma unroll
        for (int q = 0; q < 2; ++q) {
            int flat = q * 256 + t, row = flat >> 3, cg = (flat & 7) * 8;
            *(bf16x8*)&As[row][cg] = ra[q];
        }
        #pragma unroll
        for (int q = 0; q < NF; ++q) {
            int flat = q * 256 + t, row = flat >> 3, cg = (flat & 7) * 8;
            *(bf16x8*)&Bs[row][cg] = rb[q];
        }
        __syncthreads();
        #pragma unroll
        for (int kk = 0; kk < 2; ++kk) {
            const int lk = kk * 32 + (lane >> 4) * 8;
            bf16x8 af[2], bfr[NF];
            #pragma unroll
            for (int fm = 0; fm < 2; ++fm)
                af[fm] = *(bf16x8*)&As[wr * 32 + fm * 16 + lr][lk];
            #pragma unroll
            for (int fn = 0; fn < NF; ++fn)
                bfr[fn] = *(bf16x8*)&Bs[wc * (NF * 16) + fn * 16 + lr][lk];
            #pragma unroll
            for (int fm = 0; fm < 2; ++fm)
                #pragma unroll
                for (int fn = 0; fn < NF; ++fn)
                    acc[fm][fn] = __builtin_amdgcn_mfma_f32_16x16x32_bf16(
                        af[fm], bfr[fn], acc[fm][fn], 0, 0, 0);
        }
    }
}

// ---------------- fused projections: ny 0-1 value->bf16, 2-3 offraw, 4 logits ----------------
__global__ __launch_bounds__(256) void proj_bf(
    const unsigned short* __restrict__ x_bf, const unsigned short* __restrict__ xp_bf,
    const unsigned short* __restrict__ WvT, const float* __restrict__ bv,
    const unsigned short* __restrict__ WofT, const float* __restrict__ bof,
    const unsigned short* __restrict__ WatT, const float* __restrict__ bat,
    unsigned short* __restrict__ value_bf, float* __restrict__ offraw,
    float* __restrict__ logits)
{
    __shared__ short As[64][72];
    __shared__ short Bs[128][72];
    const int ny = blockIdx.y;
    const unsigned short* Ap; const unsigned short* Bp;
    const float* bias; int Nout, nb;
    if (ny < 2)      { Ap = x_bf;  Bp = WvT;  bias = bv;  Nout = 256; nb = ny; }
    else if (ny < 4) { Ap = xp_bf; Bp = WofT; bias = bof; Nout = 256; nb = ny - 2; }
    else             { Ap = xp_bf; Bp = WatT; bias = bat; Nout = 128; nb = 0; }
    const int mBase = blockIdx.x * 64, nBase = nb * 128;

    f32x4 acc[2][4];
    gemm_core<4>(Ap, Bp, 256, mBase, nBase, As, Bs, acc);

    const int lane = threadIdx.x & 63;
    const int wave = threadIdx.x >> 6;
    const int wr = wave >> 1, wc = wave & 1;
    #pragma unroll
    for (int fm = 0; fm < 2; ++fm)
        #pragma unroll
        for (int fn = 0; fn < 4; ++fn)
            #pragma unroll
            for (int r = 0; r < 4; ++r) {
                int m = mBase + wr * 32 + fm * 16 + (lane >> 4) * 4 + r;
                int n = nBase + wc * 64 + fn * 16 + (lane & 15);
                float v = acc[fm][fn][r] + bias[n];
                if (ny < 2) value_bf[(long)m * 256 + n] = (unsigned short)f2bf(v);
                else if (ny < 4) offraw[(long)m * 256 + n] = v;
                else logits[(long)m * 128 + n] = v;
            }
}

// ---------------- W1 GEMM: relu, bf16 out, 64x256 tile ----------------
__global__ __launch_bounds__(256) void gemm_relu(
    const unsigned short* __restrict__ A, const unsigned short* __restrict__ Bt,
    const float* __restrict__ bias, unsigned short* __restrict__ outB)
{
    __shared__ short As[64][72];
    __shared__ short Bs[256][72];
    const int mBase = blockIdx.x * 64, nBase = blockIdx.y * 256;
    f32x4 acc[2][8];
    gemm_core<8>(A, Bt, 256, mBase, nBase, As, Bs, acc);

    const int lane = threadIdx.x & 63;
    const int wave = threadIdx.x >> 6;
    const int wr = wave >> 1, wc = wave & 1;
    #pragma unroll
    for (int fm = 0; fm < 2; ++fm)
        #pragma unroll
        for (int fn = 0; fn < 8; ++fn)
            #pragma unroll
            for (int r = 0; r < 4; ++r) {
                int m = mBase + wr * 32 + fm * 16 + (lane >> 4) * 4 + r;
                int n = nBase + wc * 128 + fn * 16 + (lane & 15);
                float v = fmaxf(acc[fm][fn][r] + bias[n], 0.f);
                outB[(long)m * 1024 + n] = (unsigned short)f2bf(v);
            }
}

// ---------------- GEMM (N=256, full row) + residual + LayerNorm epilogue ----------------
// out = LN(A@Bt^T + bias + res); outF fp32; optional outB=bf16(out), outXp=bf16(out+pos)
__global__ __launch_bounds__(256) void gemm_ln(
    const unsigned short* __restrict__ A, const unsigned short* __restrict__ Bt,
    const float* __restrict__ bias, const float* __restrict__ res,
    const float* __restrict__ g, const float* __restrict__ b,
    float* __restrict__ outF, unsigned short* __restrict__ outB,
    const float* __restrict__ pos, unsigned short* __restrict__ outXp,
    int K)
{
    __shared__ short As[64][72];
    __shared__ short Bs[256][72];
    __shared__ float2 sRed[2][64];
    const int mBase = blockIdx.x * 64;
    f32x4 acc[2][8];
    gemm_core<8>(A, Bt, K, mBase, 0, As, Bs, acc);

    const int lane = threadIdx.x & 63;
    const int wave = threadIdx.x >> 6;
    const int wr = wave >> 1, wc = wave & 1;
    const int lc = lane & 15, lq = lane >> 4;

    float g_c[8], b_c[8];
    int ncol[8];
    #pragma unroll
    for (int fn = 0; fn < 8; ++fn) {
        int n = wc * 128 + fn * 16 + lc;
        ncol[fn] = n;
        g_c[fn] = g[n];
        b_c[fn] = b[n];
    }

    // v = acc + bias + res (overwrite acc)
    #pragma unroll
    for (int fm = 0; fm < 2; ++fm)
        #pragma unroll
        for (int r = 0; r < 4; ++r) {
            int m = mBase + wr * 32 + fm * 16 + lq * 4 + r;
            #pragma unroll
            for (int fn = 0; fn < 8; ++fn)
                acc[fm][fn][r] += bias[ncol[fn]] + res[(long)m * 256 + ncol[fn]];
        }

    // per-row partial sums -> 16-lane reduce -> LDS
    #pragma unroll
    for (int fm = 0; fm < 2; ++fm)
        #pragma unroll
        for (int r = 0; r < 4; ++r) {
            float s1 = 0.f, s2 = 0.f;
            #pragma unroll
            for (int fn = 0; fn < 8; ++fn) {
                float vv = acc[fm][fn][r];
                s1 += vv; s2 += vv * vv;
            }
            #pragma unroll
            for (int o = 1; o < 16; o <<= 1) {
                s1 += __shfl_xor(s1, o);
                s2 += __shfl_xor(s2, o);
            }
            if (lc == 0) {
                float2 pr; pr.x = s1; pr.y = s2;
                sRed[wc][wr * 32 + fm * 16 + lq * 4 + r] = pr;
            }
        }
    __syncthreads();

    #pragma unroll
    for (int fm = 0; fm < 2; ++fm)
        #pragma unroll
        for (int r = 0; r < 4; ++r) {
            int row = wr * 32 + fm * 16 + lq * 4 + r;
            float2 a0 = sRed[0][row], a1 = sRed[1][row];
            float mean = (a0.x + a1.x) * (1.f / 256.f);
            float var  = (a0.y + a1.y) * (1.f / 256.f) - mean * mean;
            float rstd = rsqrtf(var + 1e-5f);
            long mb = (long)(mBase + row) * 256;
            #pragma unroll
            for (int fn = 0; fn < 8; ++fn) {
                float o = (acc[fm][fn][r] - mean) * rstd * g_c[fn] + b_c[fn];
                outF[mb + ncol[fn]] = o;
                if (outB) outB[mb + ncol[fn]] = (unsigned short)f2bf(o);
                if (outXp) outXp[mb + ncol[fn]] =
                    (unsigned short)f2bf(o + pos[mb + ncol[fn]]);
            }
        }
}

// ---------------- MSDA sampling (bf16 value gather) ----------------
__global__ __launch_bounds__(256) void msda_sample(
    const unsigned short* __restrict__ value, const float* __restrict__ offraw,
    const float* __restrict__ logits, const float* __restrict__ vr,
    unsigned short* __restrict__ outB)
{
    const int s = blockIdx.x;
    const int t = threadIdx.x;

    __shared__ int4   sIdx[128];
    __shared__ float4 sW[128];
    __shared__ float4 sPart[192];

    if (t < 128) {
        const int pt = t & 15;
        const int l = pt >> 2;

        float lg = logits[s * 128 + t];
        float m = lg;
        #pragma unroll
        for (int o = 1; o < 16; o <<= 1) m = fmaxf(m, __shfl_xor(m, o));
        float e = expf(lg - m);
        float sum = e;
        #pragma unroll
        for (int o = 1; o < 16; o <<= 1) sum += __shfl_xor(sum, o);
        float aw = e / sum;

        int ls = (s < 4096) ? 0 : (s < 5120) ? 1 : (s < 5376) ? 2 : 3;
        int lw = c_logW[ls];
        int Wq = c_HW[ls];
        int rem = s - c_start[ls];
        int qi = rem >> lw, qj = rem & (Wq - 1);
        float xh = (qj + 0.5f) / (vr[ls * 2 + 1] * (float)Wq);
        float yh = (qi + 0.5f) / (vr[ls * 2 + 0] * (float)Wq);

        const int Wl = c_HW[l], sl = c_start[l];
        const float fW = (float)Wl;
        float refx = xh * vr[l * 2 + 1];
        float refy = yh * vr[l * 2 + 0];
        float ox = offraw[s * 256 + t * 2];
        float oy = offraw[s * 256 + t * 2 + 1];
        float x = refx * fW + ox - 0.5f;
        float y = refy * fW + oy - 0.5f;
        float x0f = floorf(x), y0f = floorf(y);
        float fx = x - x0f, fy = y - y0f;
        int x0 = (int)x0f, y0 = (int)y0f;
        int x1 = x0 + 1, y1 = y0 + 1;
        float vx0 = (x0 >= 0 && x0 < Wl) ? 1.f : 0.f;
        float vx1 = (x1 >= 0 && x1 < Wl) ? 1.f : 0.f;
        float vy0 = (y0 >= 0 && y0 < Wl) ? 1.f : 0.f;
        float vy1 = (y1 >= 0 && y1 < Wl) ? 1.f : 0.f;
        int cx0 = min(max(x0, 0), Wl - 1), cx1 = min(max(x1, 0), Wl - 1);
        int cy0 = min(max(y0, 0), Wl - 1), cy1 = min(max(y1, 0), Wl - 1);

        int4 id;
        id.x = sl + cy0 * Wl + cx0;
        id.y = sl + cy0 * Wl + cx1;
        id.z = sl + cy1 * Wl + cx0;
        id.w = sl + cy1 * Wl + cx1;
        sIdx[t] = id;
        float4 w4;
        w4.x = aw * (1.f - fx) * (1.f - fy) * vx0 * vy0;
        w4.y = aw * fx * (1.f - fy) * vx1 * vy0;
        w4.z = aw * (1.f - fx) * fy * vx0 * vy1;
        w4.w = aw * fx * fy * vx1 * vy1;
        sW[t] = w4;
    }
    __syncthreads();

    const int pg = t >> 6;
    const int h  = (t >> 3) & 7;
    const int dq = t & 7;
    const int cb = h * 32 + dq * 4;

    f32x4 acc = (f32x4){0.f, 0.f, 0.f, 0.f};
    #pragma unroll
    for (int p = 0; p < 4; ++p) {
        const int e = h * 16 + pg * 4 + p;
        int4 id = sIdx[e];
        float4 w = sW[e];
        ushort4 u0 = *(const ushort4*)(value + id.x * 256 + cb);
        ushort4 u1 = *(const ushort4*)(value + id.y * 256 + cb);
        ushort4 u2 = *(const ushort4*)(value + id.z * 256 + cb);
        ushort4 u3 = *(const ushort4*)(value + id.w * 256 + cb);
        f32x4 v0 = (f32x4){bf2f(u0.x), bf2f(u0.y), bf2f(u0.z), bf2f(u0.w)};
        f32x4 v1 = (f32x4){bf2f(u1.x), bf2f(u1.y), bf2f(u1.z), bf2f(u1.w)};
        f32x4 v2 = (f32x4){bf2f(u2.x), bf2f(u2.y), bf2f(u2.z), bf2f(u2.w)};
        f32x4 v3 = (f32x4){bf2f(u3.x), bf2f(u3.y), bf2f(u3.z), bf2f(u3.w)};
        acc += w.x * v0 + w.y * v1 + w.z * v2 + w.w * v3;
    }

    if (pg > 0) {
        float4 st; st.x = acc[0]; st.y = acc[1]; st.z = acc[2]; st.w = acc[3];
        sPart[(pg - 1) * 64 + (t & 63)] = st;
    }
    __syncthreads();
    if (pg == 0) {
        float4 p0 = sPart[t], p1 = sPart[64 + t], p2 = sPart[128 + t];
        acc[0] += p0.x + p1.x + p2.x;
        acc[1] += p0.y + p1.y + p2.y;
        acc[2] += p0.z + p1.z + p2.z;
        acc[3] += p0.w + p1.w + p2.w;
        ushort4 o;
        o.x = (unsigned short)f2bf(acc[0]);
        o.y = (unsigned short)f2bf(acc[1]);
        o.z = (unsigned short)f2bf(acc[2]);
        o.w = (unsigned short)f2bf(acc[3]);
        *(ushort4*)(outB + (long)s * 256 + cb) = o;
    }
}

extern "C" void kernel_launch(void* const* d_in, const int* in_sizes, int n_in,
                              void* d_out, int out_size, void* d_ws, size_t ws_size,
                              hipStream_t stream) {
    const float* src   = (const float*)d_in[0];
    const float* pos   = (const float*)d_in[1];
    const float* vr    = (const float*)d_in[2];
    const float* Wv    = (const float*)d_in[5];
    const float* bv    = (const float*)d_in[6];
    const float* Woff  = (const float*)d_in[7];
    const float* boff  = (const float*)d_in[8];
    const float* Wattn = (const float*)d_in[9];
    const float* battn = (const float*)d_in[10];
    const float* Wout  = (const float*)d_in[11];
    const float* bout  = (const float*)d_in[12];
    const float* ln1g  = (const float*)d_in[13];
    const float* ln1b  = (const float*)d_in[14];
    const float* W1    = (const float*)d_in[15];
    const float* b1    = (const float*)d_in[16];
    const float* W2    = (const float*)d_in[17];
    const float* b2    = (const float*)d_in[18];
    const float* ln2g  = (const float*)d_in[19];
    const float* ln2b  = (const float*)d_in[20];

    const int S = S_TOT, C = C_DIM;
    const long SC = (long)S * C;

    float* ws     = (float*)d_ws;
    float* xbuf   = ws;                        // SC f32
    float* offraw = xbuf + SC;                 // SC f32
    float* logits = offraw + SC;               // S*128 f32
    unsigned short* value_bf = (unsigned short*)(logits + (long)S * 128); // SC
    unsigned short* x_bf     = value_bf + SC;  // SC
    unsigned short* xp_bf    = x_bf + SC;      // SC
    unsigned short* msda_bf  = xp_bf + SC;     // SC
    unsigned short* hbuf_bf  = msda_bf + SC;   // S*F
    unsigned short* WT       = hbuf_bf + (long)S * F_DIM;

    const unsigned short* WvT  = WT + 0;
    const unsigned short* WofT = WT + 393216;
    const unsigned short* WatT = WT + 786432;
    const unsigned short* WouT = WT + 983040;
    const unsigned short* W1T  = WT + 1376256;
    const unsigned short* W2T  = WT + 2949120;

    prep_weights<<<1104, 256, 0, stream>>>(Wv, Woff, Wattn, Wout, W1, W2, WT);
    prep_x0<<<1360, 256, 0, stream>>>(src, pos, x_bf, xp_bf);

    const float* x = src;   // fp32 residual stream
    for (int i = 0; i < N_LAYERS; ++i) {
        proj_bf<<<dim3(85, 5), 256, 0, stream>>>(
            x_bf, xp_bf,
            WvT + (long)i * 65536, bv + i * C,
            WofT + (long)i * 65536, boff + (long)i * 256,
            WatT + (long)i * 32768, battn + (long)i * 128,
            value_bf, offraw, logits);

        msda_sample<<<S, 256, 0, stream>>>(value_bf, offraw, logits, vr, msda_bf);

        // xbuf = LN1(msda @ Wout^T + bout + x); also x_bf = bf16(xbuf)
        gemm_ln<<<85, 256, 0, stream>>>(
            msda_bf, WouT + (long)i * 65536, bout + i * C, x,
            ln1g + i * C, ln1b + i * C, xbuf, x_bf, nullptr, nullptr, 256);

        // hbuf = relu(x_bf @ W1^T + b1)
        gemm_relu<<<dim3(85, 4), 256, 0, stream>>>(
            x_bf, W1T + (long)i * 262144, b1 + (long)i * F_DIM, hbuf_bf);

        // LN2(hbuf @ W2^T + b2 + xbuf) -> {xbuf|d_out}, x_bf, xp_bf
        if (i == N_LAYERS - 1) {
            gemm_ln<<<85, 256, 0, stream>>>(
                hbuf_bf, W2T + (long)i * 262144, b2 + i * C, xbuf,
                ln2g + i * C, ln2b + i * C, (float*)d_out,
                nullptr, nullptr, nullptr, 1024);
        } else {
            gemm_ln<<<85, 256, 0, stream>>>(
                hbuf_bf, W2T + (long)i * 262144, b2 + i * C, xbuf,
                ln2g + i * C, ln2b + i * C, xbuf, x_bf, pos, xp_bf, 1024);
        }
        x = xbuf;
    }
}

// Round 6
// 505.072 us; speedup vs baseline: 1.0489x; 1.0489x over previous
//
#include <hip/hip_runtime.h>
#include <hip/hip_bf16.h>

#define S_TOT 5440
#define C_DIM 256
#define F_DIM 1024
#define N_LAYERS 6

__device__ __constant__ int c_HW[4]    = {64, 32, 16, 8};
__device__ __constant__ int c_logW[4]  = {6, 5, 4, 3};
__device__ __constant__ int c_start[4] = {0, 4096, 5120, 5376};

typedef __attribute__((ext_vector_type(8))) short bf16x8;
typedef __attribute__((ext_vector_type(4))) float f32x4;

__device__ __forceinline__ short f2bf(float f) {
    __hip_bfloat16 h = __float2bfloat16(f);
    return *reinterpret_cast<short*>(&h);
}
__device__ __forceinline__ float bf2f(unsigned short u) {
    union { unsigned int i; float f; } c; c.i = ((unsigned int)u) << 16; return c.f;
}

// ---------------- weight prep: fp32 [K][N] -> bf16 [N][K], all 36 matrices ----------------
__global__ __launch_bounds__(256) void prep_weights(
    const float* __restrict__ Wv, const float* __restrict__ Woff,
    const float* __restrict__ Wattn, const float* __restrict__ Wout,
    const float* __restrict__ W1, const float* __restrict__ W2,
    unsigned short* __restrict__ WT)
{
    __shared__ short T[64][72];
    const int bid = blockIdx.x;
    const int layer = bid / 184;
    const int r = bid % 184;
    const float* src; unsigned short* dst; int K, N, kb, nb;
    if (r < 16)       { src = Wv    + (long)layer*65536;  dst = WT + 0       + (long)layer*65536;  K=256;  N=256;  kb=r&3;        nb=r>>2; }
    else if (r < 32)  { src = Woff  + (long)layer*65536;  dst = WT + 393216  + (long)layer*65536;  K=256;  N=256;  kb=(r-16)&3;   nb=(r-16)>>2; }
    else if (r < 40)  { src = Wattn + (long)layer*32768;  dst = WT + 786432  + (long)layer*32768;  K=256;  N=128;  kb=(r-32)&3;   nb=(r-32)>>2; }
    else if (r < 56)  { src = Wout  + (long)layer*65536;  dst = WT + 983040  + (long)layer*65536;  K=256;  N=256;  kb=(r-40)&3;   nb=(r-40)>>2; }
    else if (r < 120) { src = W1    + (long)layer*262144; dst = WT + 1376256 + (long)layer*262144; K=256;  N=1024; kb=(r-56)&3;   nb=(r-56)>>2; }
    else              { src = W2    + (long)layer*262144; dst = WT + 2949120 + (long)layer*262144; K=1024; N=256;  kb=(r-120)&15; nb=(r-120)>>4; }
    const int k0 = kb * 64, n0 = nb * 64;
    const int t = threadIdx.x;
    {
        const int row = t >> 2, cg = (t & 3) * 16;
        const float* sp = src + (long)(k0 + row) * N + n0 + cg;
        float4 v0 = *(const float4*)sp;
        float4 v1 = *(const float4*)(sp + 4);
        float4 v2 = *(const float4*)(sp + 8);
        float4 v3 = *(const float4*)(sp + 12);
        short tmp[16];
        tmp[0]=f2bf(v0.x); tmp[1]=f2bf(v0.y); tmp[2]=f2bf(v0.z); tmp[3]=f2bf(v0.w);
        tmp[4]=f2bf(v1.x); tmp[5]=f2bf(v1.y); tmp[6]=f2bf(v1.z); tmp[7]=f2bf(v1.w);
        tmp[8]=f2bf(v2.x); tmp[9]=f2bf(v2.y); tmp[10]=f2bf(v2.z); tmp[11]=f2bf(v2.w);
        tmp[12]=f2bf(v3.x); tmp[13]=f2bf(v3.y); tmp[14]=f2bf(v3.z); tmp[15]=f2bf(v3.w);
        *(bf16x8*)&T[row][cg]     = *(bf16x8*)&tmp[0];
        *(bf16x8*)&T[row][cg + 8] = *(bf16x8*)&tmp[8];
    }
    __syncthreads();
    {
        const int n = t >> 2, kg = (t & 3) * 16;
        short o[16];
        #pragma unroll
        for (int j = 0; j < 16; ++j) o[j] = T[kg + j][n];
        unsigned short* dp = dst + (long)(n0 + n) * K + k0 + kg;
        *(bf16x8*)dp       = *(bf16x8*)&o[0];
        *(bf16x8*)(dp + 8) = *(bf16x8*)&o[8];
    }
}

// ============ A-prep: load fp32 64x256 tile, optional LN, optional +pos, -> bf16 LDS ============
__device__ __forceinline__ void prep_A(
    const float* __restrict__ Ain, const float* __restrict__ g,
    const float* __restrict__ b, const float* __restrict__ pos,
    float* __restrict__ xout, int mBase, int doLN,
    short (*As)[264])
{
    const int t = threadIdx.x;
    const int row = t >> 2, q4 = t & 3;
    const long gbase = (long)(mBase + row) * 256 + q4 * 64;
    float va[64];
    #pragma unroll
    for (int j = 0; j < 16; ++j) {
        float4 v = *(const float4*)(Ain + gbase + j * 4);
        va[j*4+0] = v.x; va[j*4+1] = v.y; va[j*4+2] = v.z; va[j*4+3] = v.w;
    }
    if (doLN) {
        float s1 = 0.f, s2 = 0.f;
        #pragma unroll
        for (int j = 0; j < 64; ++j) { s1 += va[j]; s2 += va[j] * va[j]; }
        s1 += __shfl_xor(s1, 1); s2 += __shfl_xor(s2, 1);
        s1 += __shfl_xor(s1, 2); s2 += __shfl_xor(s2, 2);
        const float mean = s1 * (1.f / 256.f);
        const float var  = s2 * (1.f / 256.f) - mean * mean;
        const float rstd = rsqrtf(var + 1e-5f);
        #pragma unroll
        for (int j = 0; j < 16; ++j) {
            float4 g4 = *(const float4*)(g + q4 * 64 + j * 4);
            float4 b4 = *(const float4*)(b + q4 * 64 + j * 4);
            va[j*4+0] = (va[j*4+0] - mean) * rstd * g4.x + b4.x;
            va[j*4+1] = (va[j*4+1] - mean) * rstd * g4.y + b4.y;
            va[j*4+2] = (va[j*4+2] - mean) * rstd * g4.z + b4.z;
            va[j*4+3] = (va[j*4+3] - mean) * rstd * g4.w + b4.w;
        }
    }
    if (xout) {
        #pragma unroll
        for (int j = 0; j < 16; ++j) {
            float4 v;
            v.x = va[j*4+0]; v.y = va[j*4+1]; v.z = va[j*4+2]; v.w = va[j*4+3];
            *(float4*)(xout + gbase + j * 4) = v;
        }
    }
    if (pos) {
        #pragma unroll
        for (int j = 0; j < 16; ++j) {
            float4 p = *(const float4*)(pos + gbase + j * 4);
            va[j*4+0] += p.x; va[j*4+1] += p.y; va[j*4+2] += p.z; va[j*4+3] += p.w;
        }
    }
    #pragma unroll
    for (int j8 = 0; j8 < 8; ++j8) {
        short tmp[8];
        #pragma unroll
        for (int e = 0; e < 8; ++e) tmp[e] = f2bf(va[j8 * 8 + e]);
        *(bf16x8*)&As[row][q4 * 64 + j8 * 8] = *(bf16x8*)tmp;
    }
}

// ============ GEMM core with A resident in LDS (K=256), B streamed ============
template<int NF>
__device__ __forceinline__ void core_Alds(
    const unsigned short* __restrict__ Bt, int nBase,
    const short (*As)[264], short (*Bs)[72], f32x4 (&acc)[2][NF])
{
    const int t = threadIdx.x;
    const int lane = t & 63, wave = t >> 6;
    const int wr = wave >> 1, wc = wave & 1;
    const int lr = lane & 15;

    #pragma unroll
    for (int i = 0; i < 2; ++i)
        #pragma unroll
        for (int j = 0; j < NF; ++j)
            acc[i][j] = (f32x4){0.f, 0.f, 0.f, 0.f};

    for (int k0 = 0; k0 < 256; k0 += 64) {
        bf16x8 rb[NF];
        #pragma unroll
        for (int q = 0; q < NF; ++q) {
            int flat = q * 256 + t, row = flat >> 3, cg = (flat & 7) * 8;
            rb[q] = *(const bf16x8*)(Bt + (long)(nBase + row) * 256 + k0 + cg);
        }
        __syncthreads();
        #pragma unroll
        for (int q = 0; q < NF; ++q) {
            int flat = q * 256 + t, row = flat >> 3, cg = (flat & 7) * 8;
            *(bf16x8*)&Bs[row][cg] = rb[q];
        }
        __syncthreads();
        #pragma unroll
        for (int kk = 0; kk < 2; ++kk) {
            const int lks = kk * 32 + (lane >> 4) * 8;
            bf16x8 af[2], bfr[NF];
            #pragma unroll
            for (int fm = 0; fm < 2; ++fm)
                af[fm] = *(const bf16x8*)&As[wr * 32 + fm * 16 + lr][k0 + lks];
            #pragma unroll
            for (int fn = 0; fn < NF; ++fn)
                bfr[fn] = *(bf16x8*)&Bs[wc * (NF * 16) + fn * 16 + lr][lks];
            #pragma unroll
            for (int fm = 0; fm < 2; ++fm)
                #pragma unroll
                for (int fn = 0; fn < NF; ++fn)
                    acc[fm][fn] = __builtin_amdgcn_mfma_f32_16x16x32_bf16(
                        af[fm], bfr[fn], acc[fm][fn], 0, 0, 0);
        }
    }
}

// ============ GEMM core with bf16 A from global (round-4 proven) ============
template<int NF>
__device__ __forceinline__ void gemm_core(
    const unsigned short* __restrict__ A, const unsigned short* __restrict__ Bt,
    int K, int mBase, int nBase, short (*As)[72], short (*Bs)[72],
    f32x4 (&acc)[2][NF])
{
    const int t = threadIdx.x;
    const int lane = t & 63, wave = t >> 6;
    const int wr = wave >> 1, wc = wave & 1;
    const int lr = lane & 15;

    #pragma unroll
    for (int i = 0; i < 2; ++i)
        #pragma unroll
        for (int j = 0; j < NF; ++j)
            acc[i][j] = (f32x4){0.f, 0.f, 0.f, 0.f};

    for (int k0 = 0; k0 < K; k0 += 64) {
        bf16x8 ra[2], rb[NF];
        #pragma unroll
        for (int q = 0; q < 2; ++q) {
            int flat = q * 256 + t, row = flat >> 3, cg = (flat & 7) * 8;
            ra[q] = *(const bf16x8*)(A + (long)(mBase + row) * K + k0 + cg);
        }
        #pragma unroll
        for (int q = 0; q < NF; ++q) {
            int flat = q * 256 + t, row = flat >> 3, cg = (flat & 7) * 8;
            rb[q] = *(const bf16x8*)(Bt + (long)(nBase + row) * K + k0 + cg);
        }
        __syncthreads();
        #pragma unroll
        for (int q = 0; q < 2; ++q) {
            int flat = q * 256 + t, row = flat >> 3, cg = (flat & 7) * 8;
            *(bf16x8*)&As[row][cg] = ra[q];
        }
        #pragma unroll
        for (int q = 0; q < NF; ++q) {
            int flat = q * 256 + t, row = flat >> 3, cg = (flat & 7) * 8;
            *(bf16x8*)&Bs[row][cg] = rb[q];
        }
        __syncthreads();
        #pragma unroll
        for (int kk = 0; kk < 2; ++kk) {
            const int lks = kk * 32 + (lane >> 4) * 8;
            bf16x8 af[2], bfr[NF];
            #pragma unroll
            for (int fm = 0; fm < 2; ++fm)
                af[fm] = *(bf16x8*)&As[wr * 32 + fm * 16 + lr][lks];
            #pragma unroll
            for (int fn = 0; fn < NF; ++fn)
                bfr[fn] = *(bf16x8*)&Bs[wc * (NF * 16) + fn * 16 + lr][lks];
            #pragma unroll
            for (int fm = 0; fm < 2; ++fm)
                #pragma unroll
                for (int fn = 0; fn < NF; ++fn)
                    acc[fm][fn] = __builtin_amdgcn_mfma_f32_16x16x32_bf16(
                        af[fm], bfr[fn], acc[fm][fn], 0, 0, 0);
        }
    }
}

// ---------------- fused LN2 + projections (grid 85 x 5) ----------------
// ny 0-1: value = LN(x)@Wv        -> bf16
// ny 2-3: offraw = (LN(x)+pos)@Woff -> f32
// ny 4  : logits = (LN(x)+pos)@Wattn -> f32
// ny==0 (doLN) also writes xcur = LN(x) fp32 (residual stream).
__global__ __launch_bounds__(256) void proj_ln(
    const float* __restrict__ Ain, const float* __restrict__ pos,
    const float* __restrict__ g, const float* __restrict__ b,
    const unsigned short* __restrict__ WvT, const float* __restrict__ bv,
    const unsigned short* __restrict__ WofT, const float* __restrict__ bof,
    const unsigned short* __restrict__ WatT, const float* __restrict__ bat,
    unsigned short* __restrict__ value_bf, float* __restrict__ offraw,
    float* __restrict__ logits, float* __restrict__ xcur, int doLN)
{
    __shared__ short As[64][264];
    __shared__ short Bs[128][72];
    const int ny = blockIdx.y, mBase = blockIdx.x * 64;
    const unsigned short* Bp; const float* bias; int nBase, kind;
    if (ny < 2)      { Bp = WvT;  bias = bv;  nBase = ny * 128;       kind = 0; }
    else if (ny < 4) { Bp = WofT; bias = bof; nBase = (ny - 2) * 128; kind = 1; }
    else             { Bp = WatT; bias = bat; nBase = 0;              kind = 2; }

    prep_A(Ain, g, b, (kind > 0) ? pos : nullptr,
           (doLN && ny == 0) ? xcur : nullptr, mBase, doLN, As);

    f32x4 acc[2][4];
    core_Alds<4>(Bp, nBase, As, Bs, acc);

    const int lane = threadIdx.x & 63, wave = threadIdx.x >> 6;
    const int wr = wave >> 1, wc = wave & 1;
    #pragma unroll
    for (int fm = 0; fm < 2; ++fm)
        #pragma unroll
        for (int fn = 0; fn < 4; ++fn)
            #pragma unroll
            for (int r = 0; r < 4; ++r) {
                int m = mBase + wr * 32 + fm * 16 + (lane >> 4) * 4 + r;
                int n = nBase + wc * 64 + fn * 16 + (lane & 15);
                float v = acc[fm][fn][r] + bias[n];
                if (kind == 0)      value_bf[(long)m * 256 + n] = (unsigned short)f2bf(v);
                else if (kind == 1) offraw[(long)m * 256 + n] = v;
                else                logits[(long)m * 128 + n] = v;
            }
}

// ---------------- fused LN1 + W1 GEMM + relu (grid 85 x 8) ----------------
__global__ __launch_bounds__(256) void gemm_w1ln(
    const float* __restrict__ Ain, const float* __restrict__ g,
    const float* __restrict__ b, const unsigned short* __restrict__ W1T,
    const float* __restrict__ bias, unsigned short* __restrict__ hbuf,
    float* __restrict__ xout)
{
    __shared__ short As[64][264];
    __shared__ short Bs[128][72];
    const int mBase = blockIdx.x * 64, nBase = blockIdx.y * 128;

    prep_A(Ain, g, b, nullptr, (blockIdx.y == 0) ? xout : nullptr, mBase, 1, As);

    f32x4 acc[2][4];
    core_Alds<4>(W1T, nBase, As, Bs, acc);

    const int lane = threadIdx.x & 63, wave = threadIdx.x >> 6;
    const int wr = wave >> 1, wc = wave & 1;
    #pragma unroll
    for (int fm = 0; fm < 2; ++fm)
        #pragma unroll
        for (int fn = 0; fn < 4; ++fn)
            #pragma unroll
            for (int r = 0; r < 4; ++r) {
                int m = mBase + wr * 32 + fm * 16 + (lane >> 4) * 4 + r;
                int n = nBase + wc * 64 + fn * 16 + (lane & 15);
                float v = fmaxf(acc[fm][fn][r] + bias[n], 0.f);
                hbuf[(long)m * 1024 + n] = (unsigned short)f2bf(v);
            }
}

// ---------------- plain GEMM (N=256) + bias + residual -> fp32 (grid 85 x 4) ----------------
__global__ __launch_bounds__(256) void gemm_res(
    const unsigned short* __restrict__ A, const unsigned short* __restrict__ Bt,
    const float* __restrict__ bias, const float* __restrict__ res,
    float* __restrict__ out, int K)
{
    __shared__ short As[64][72];
    __shared__ short Bs[64][72];
    const int mBase = blockIdx.x * 64, nBase = blockIdx.y * 64;
    f32x4 acc[2][2];
    gemm_core<2>(A, Bt, K, mBase, nBase, As, Bs, acc);

    const int lane = threadIdx.x & 63, wave = threadIdx.x >> 6;
    const int wr = wave >> 1, wc = wave & 1;
    #pragma unroll
    for (int fm = 0; fm < 2; ++fm)
        #pragma unroll
        for (int fn = 0; fn < 2; ++fn)
            #pragma unroll
            for (int r = 0; r < 4; ++r) {
                int m = mBase + wr * 32 + fm * 16 + (lane >> 4) * 4 + r;
                int n = nBase + wc * 32 + fn * 16 + (lane & 15);
                out[(long)m * 256 + n] = acc[fm][fn][r] + bias[n] + res[(long)m * 256 + n];
            }
}

// ---------------- MSDA sampling v3: 2 queries/block, 16B gathers ----------------
__global__ __launch_bounds__(256) void msda2(
    const unsigned short* __restrict__ value, const float* __restrict__ offraw,
    const float* __restrict__ logits, const float* __restrict__ vr,
    unsigned short* __restrict__ outB)
{
    const int t = threadIdx.x;
    const int q = t >> 7, tt = t & 127;
    const int s = blockIdx.x * 2 + q;

    __shared__ int4   sIdx[2][128];
    __shared__ float4 sW[2][128];
    __shared__ float  sPart[2][3][32][8];

    {
        const int pt = tt & 15, l = pt >> 2;

        float lg = logits[(long)s * 128 + tt];
        float m = lg;
        #pragma unroll
        for (int o = 1; o < 16; o <<= 1) m = fmaxf(m, __shfl_xor(m, o));
        float e = expf(lg - m);
        float sum = e;
        #pragma unroll
        for (int o = 1; o < 16; o <<= 1) sum += __shfl_xor(sum, o);
        float aw = e / sum;

        int ls = (s < 4096) ? 0 : (s < 5120) ? 1 : (s < 5376) ? 2 : 3;
        int lw = c_logW[ls];
        int Wq = c_HW[ls];
        int rem = s - c_start[ls];
        int qi = rem >> lw, qj = rem & (Wq - 1);
        float xh = (qj + 0.5f) / (vr[ls * 2 + 1] * (float)Wq);
        float yh = (qi + 0.5f) / (vr[ls * 2 + 0] * (float)Wq);

        const int Wl = c_HW[l], sl = c_start[l];
        const float fW = (float)Wl;
        float refx = xh * vr[l * 2 + 1];
        float refy = yh * vr[l * 2 + 0];
        float2 oxy = *(const float2*)(offraw + (long)s * 256 + tt * 2);
        float x = refx * fW + oxy.x - 0.5f;
        float y = refy * fW + oxy.y - 0.5f;
        float x0f = floorf(x), y0f = floorf(y);
        float fx = x - x0f, fy = y - y0f;
        int x0 = (int)x0f, y0 = (int)y0f;
        int x1 = x0 + 1, y1 = y0 + 1;
        float vx0 = (x0 >= 0 && x0 < Wl) ? 1.f : 0.f;
        float vx1 = (x1 >= 0 && x1 < Wl) ? 1.f : 0.f;
        float vy0 = (y0 >= 0 && y0 < Wl) ? 1.f : 0.f;
        float vy1 = (y1 >= 0 && y1 < Wl) ? 1.f : 0.f;
        int cx0 = min(max(x0, 0), Wl - 1), cx1 = min(max(x1, 0), Wl - 1);
        int cy0 = min(max(y0, 0), Wl - 1), cy1 = min(max(y1, 0), Wl - 1);

        int4 id;
        id.x = sl + cy0 * Wl + cx0;
        id.y = sl + cy0 * Wl + cx1;
        id.z = sl + cy1 * Wl + cx0;
        id.w = sl + cy1 * Wl + cx1;
        sIdx[q][tt] = id;
        float4 w4;
        w4.x = aw * (1.f - fx) * (1.f - fy) * vx0 * vy0;
        w4.y = aw * fx * (1.f - fy) * vx1 * vy0;
        w4.z = aw * (1.f - fx) * fy * vx0 * vy1;
        w4.w = aw * fx * fy * vx1 * vy1;
        sW[q][tt] = w4;
    }
    __syncthreads();

    const int pg = tt >> 5, h = (tt >> 2) & 7, dq = tt & 3;
    const int cb = h * 32 + dq * 8;

    float acc[8] = {0.f, 0.f, 0.f, 0.f, 0.f, 0.f, 0.f, 0.f};
    #pragma unroll
    for (int p = 0; p < 4; ++p) {
        const int ei = h * 16 + pg * 4 + p;
        int4 id = sIdx[q][ei];
        float4 w = sW[q][ei];
        bf16x8 u0 = *(const bf16x8*)(value + (long)id.x * 256 + cb);
        bf16x8 u1 = *(const bf16x8*)(value + (long)id.y * 256 + cb);
        bf16x8 u2 = *(const bf16x8*)(value + (long)id.z * 256 + cb);
        bf16x8 u3 = *(const bf16x8*)(value + (long)id.w * 256 + cb);
        #pragma unroll
        for (int e8 = 0; e8 < 8; ++e8) {
            acc[e8] += w.x * bf2f((unsigned short)u0[e8])
                     + w.y * bf2f((unsigned short)u1[e8])
                     + w.z * bf2f((unsigned short)u2[e8])
                     + w.w * bf2f((unsigned short)u3[e8]);
        }
    }

    if (pg > 0) {
        float4 a0, a1;
        a0.x = acc[0]; a0.y = acc[1]; a0.z = acc[2]; a0.w = acc[3];
        a1.x = acc[4]; a1.y = acc[5]; a1.z = acc[6]; a1.w = acc[7];
        *(float4*)&sPart[q][pg - 1][h * 4 + dq][0] = a0;
        *(float4*)&sPart[q][pg - 1][h * 4 + dq][4] = a1;
    }
    __syncthreads();
    if (pg == 0) {
        #pragma unroll
        for (int e8 = 0; e8 < 8; ++e8)
            acc[e8] += sPart[q][0][h * 4 + dq][e8]
                     + sPart[q][1][h * 4 + dq][e8]
                     + sPart[q][2][h * 4 + dq][e8];
        short o[8];
        #pragma unroll
        for (int e8 = 0; e8 < 8; ++e8) o[e8] = f2bf(acc[e8]);
        *(bf16x8*)(outB + (long)s * 256 + cb) = *(bf16x8*)o;
    }
}

// ---------------- final LayerNorm: one wave per row ----------------
__global__ __launch_bounds__(256) void ln4f(
    const float* __restrict__ in, const float* __restrict__ g,
    const float* __restrict__ b, float* __restrict__ out)
{
    const int wave = threadIdx.x >> 6, lane = threadIdx.x & 63;
    const int s = blockIdx.x * 4 + wave;
    f32x4 v = *(const f32x4*)(in + (long)s * 256 + lane * 4);

    float sum = v[0] + v[1] + v[2] + v[3];
    #pragma unroll
    for (int o = 1; o < 64; o <<= 1) sum += __shfl_xor(sum, o);
    const float mean = sum * (1.f / 256.f);

    f32x4 d = v - mean;
    float sq = d[0]*d[0] + d[1]*d[1] + d[2]*d[2] + d[3]*d[3];
    #pragma unroll
    for (int o = 1; o < 64; o <<= 1) sq += __shfl_xor(sq, o);
    const float rstd = rsqrtf(sq * (1.f / 256.f) + 1e-5f);

    f32x4 gg = *(const f32x4*)(g + lane * 4);
    f32x4 bb = *(const f32x4*)(b + lane * 4);
    f32x4 o4 = d * rstd * gg + bb;
    *(f32x4*)(out + (long)s * 256 + lane * 4) = o4;
}

extern "C" void kernel_launch(void* const* d_in, const int* in_sizes, int n_in,
                              void* d_out, int out_size, void* d_ws, size_t ws_size,
                              hipStream_t stream) {
    const float* src   = (const float*)d_in[0];
    const float* pos   = (const float*)d_in[1];
    const float* vr    = (const float*)d_in[2];
    const float* Wv    = (const float*)d_in[5];
    const float* bv    = (const float*)d_in[6];
    const float* Woff  = (const float*)d_in[7];
    const float* boff  = (const float*)d_in[8];
    const float* Wattn = (const float*)d_in[9];
    const float* battn = (const float*)d_in[10];
    const float* Wout  = (const float*)d_in[11];
    const float* bout  = (const float*)d_in[12];
    const float* ln1g  = (const float*)d_in[13];
    const float* ln1b  = (const float*)d_in[14];
    const float* W1    = (const float*)d_in[15];
    const float* b1    = (const float*)d_in[16];
    const float* W2    = (const float*)d_in[17];
    const float* b2    = (const float*)d_in[18];
    const float* ln2g  = (const float*)d_in[19];
    const float* ln2b  = (const float*)d_in[20];

    const int S = S_TOT, C = C_DIM;
    const long SC = (long)S * C;

    float* ws     = (float*)d_ws;
    float* tmp2   = ws;                        // SC f32 (W2 out / proj in; also Wout out)
    float* xcur   = tmp2 + SC;                 // SC f32 (LN2 out = layer input x)
    float* offraw = xcur + SC;                 // SC f32 (also aliased as xln1 later)
    float* logits = offraw + SC;               // S*128 f32
    unsigned short* value_bf = (unsigned short*)(logits + (long)S * 128); // SC
    unsigned short* msda_bf  = value_bf + SC;  // SC
    unsigned short* hbuf_bf  = msda_bf + SC;   // S*F
    unsigned short* WT       = hbuf_bf + (long)S * F_DIM;

    float* xln1 = offraw;  // alias: offraw dead after msda2, xln1 live W1->W2

    const unsigned short* WvT  = WT + 0;
    const unsigned short* WofT = WT + 393216;
    const unsigned short* WatT = WT + 786432;
    const unsigned short* WouT = WT + 983040;
    const unsigned short* W1T  = WT + 1376256;
    const unsigned short* W2T  = WT + 2949120;

    prep_weights<<<1104, 256, 0, stream>>>(Wv, Woff, Wattn, Wout, W1, W2, WT);

    for (int i = 0; i < N_LAYERS; ++i) {
        const float* Ain = (i == 0) ? src : tmp2;
        const float* g2  = (i == 0) ? nullptr : ln2g + (long)(i - 1) * C;
        const float* bb2 = (i == 0) ? nullptr : ln2b + (long)(i - 1) * C;
        const float* resWout = (i == 0) ? src : xcur;

        proj_ln<<<dim3(85, 5), 256, 0, stream>>>(
            Ain, pos, g2, bb2,
            WvT + (long)i * 65536, bv + (long)i * C,
            WofT + (long)i * 65536, boff + (long)i * 256,
            WatT + (long)i * 32768, battn + (long)i * 128,
            value_bf, offraw, logits, xcur, (i == 0) ? 0 : 1);

        msda2<<<S / 2, 256, 0, stream>>>(value_bf, offraw, logits, vr, msda_bf);

        // tmp2 = msda @ Wout^T + bout + x
        gemm_res<<<dim3(85, 4), 256, 0, stream>>>(
            msda_bf, WouT + (long)i * 65536, bout + (long)i * C, resWout, tmp2, 256);

        // hbuf = relu(LN1(tmp2) @ W1^T + b1); xln1 = LN1(tmp2) fp32
        gemm_w1ln<<<dim3(85, 8), 256, 0, stream>>>(
            tmp2, ln1g + (long)i * C, ln1b + (long)i * C,
            W1T + (long)i * 262144, b1 + (long)i * F_DIM, hbuf_bf, xln1);

        // tmp2 = hbuf @ W2^T + b2 + xln1
        gemm_res<<<dim3(85, 4), 256, 0, stream>>>(
            hbuf_bf, W2T + (long)i * 262144, b2 + (long)i * C, xln1, tmp2, 1024);
    }

    ln4f<<<S / 4, 256, 0, stream>>>(
        tmp2, ln2g + (long)(N_LAYERS - 1) * C, ln2b + (long)(N_LAYERS - 1) * C,
        (float*)d_out);
}